// Round 1
// baseline (112.499 us; speedup 1.0000x reference)
//
#include <hip/hip_runtime.h>

// out[i, j] = x[i, j] * a[j];  x: [65536, 1024] f32, a: [1024] f32.
// Memory-bound elementwise: float4 vectorized, grid-stride, a staged in LDS.

#define XSIZE 1024
#define XSIZE4 (XSIZE / 4)   // 256 float4 column-quads

__global__ __launch_bounds__(256) void ic_adjust_kernel(
    const float* __restrict__ x,
    const float* __restrict__ a,
    float* __restrict__ out,
    long long n4) {
    __shared__ float4 a_lds[XSIZE4];

    // Stage a (4 KiB) into LDS once per block. blockDim.x == 256 == XSIZE4.
    const float4* a4 = reinterpret_cast<const float4*>(a);
    a_lds[threadIdx.x] = a4[threadIdx.x];
    __syncthreads();

    const float4* __restrict__ x4 = reinterpret_cast<const float4*>(x);
    float4* __restrict__ o4 = reinterpret_cast<float4*>(out);

    const long long stride = (long long)gridDim.x * blockDim.x;
    for (long long i = (long long)blockIdx.x * blockDim.x + threadIdx.x;
         i < n4; i += stride) {
        float4 v = x4[i];
        float4 s = a_lds[i & (XSIZE4 - 1)];  // column quad = i % 256
        v.x *= s.x;
        v.y *= s.y;
        v.z *= s.z;
        v.w *= s.w;
        o4[i] = v;
    }
}

extern "C" void kernel_launch(void* const* d_in, const int* in_sizes, int n_in,
                              void* d_out, int out_size, void* d_ws, size_t ws_size,
                              hipStream_t stream) {
    const float* x = (const float*)d_in[0];
    const float* a = (const float*)d_in[1];
    float* out = (float*)d_out;

    const long long n4 = (long long)out_size / 4;  // 16,777,216 float4s

    const int block = 256;
    long long blocks_needed = (n4 + block - 1) / block;
    int grid = (int)((blocks_needed < 2048) ? blocks_needed : 2048);

    ic_adjust_kernel<<<grid, block, 0, stream>>>(x, a, out, n4);
}